// Round 1
// baseline (239.156 us; speedup 1.0000x reference)
//
#include <hip/hip_runtime.h>
#include <hip/hip_bf16.h>

// Problem constants (fixed by setup_inputs)
#define NB   32
#define NQ   300
#define NCLS 92
#define NM   50
#define BM   (NB * NM)   // 1600 flat targets
#define BQ   (NB * NQ)   // 9600 flat preds
#define HM   NQ          // hungarian cols (queries) = 300
#define HN   NM          // hungarian rows (targets) = 50
#define PITCH 304        // LDS pitch for 50x300 cost tile
#define BIG  1e30f

__device__ __forceinline__ float wred_max(float v) {
#pragma unroll
  for (int m = 1; m < 64; m <<= 1) v = fmaxf(v, __shfl_xor(v, m, 64));
  return v;
}
__device__ __forceinline__ float wred_sum(float v) {
#pragma unroll
  for (int m = 1; m < 64; m <<= 1) v += __shfl_xor(v, m, 64);
  return v;
}

// ---------------- Kernel 1: cost matrix ----------------
// C[row, j] = -softmax(logits[row])[tl[j]] + 5*L1(pb,tb) - 2*GIoU(pb,tb)
// One wave per pred row; 4 waves x 4 rows = 16 rows per block.
#define ROWS_PER_BLOCK 16

__global__ __launch_bounds__(256) void cost_kernel(
    const float* __restrict__ logits, const float* __restrict__ pboxes,
    const int* __restrict__ tlab, const float* __restrict__ tbox,
    float* __restrict__ C) {
  __shared__ int    tl_s[BM];
  __shared__ float4 tb_s[BM];
  __shared__ float  probs_s[4][NCLS];

  int tid = threadIdx.x;
  const float4* tbv = reinterpret_cast<const float4*>(tbox);
  for (int idx = tid; idx < BM; idx += 256) {
    tl_s[idx] = tlab[idx];
    tb_s[idx] = tbv[idx];
  }
  __syncthreads();

  int wave = tid >> 6, lane = tid & 63;
  for (int r = 0; r < 4; r++) {
    int row = blockIdx.x * ROWS_PER_BLOCK + wave * 4 + r;
    const float* lrow = logits + (size_t)row * NCLS;
    // softmax stats (match jax: exp(x - max) / sum)
    float mx = -BIG;
    for (int c = lane; c < NCLS; c += 64) mx = fmaxf(mx, lrow[c]);
    mx = wred_max(mx);
    float s = 0.f;
    for (int c = lane; c < NCLS; c += 64) s += expf(lrow[c] - mx);
    s = wred_sum(s);
    for (int c = lane; c < NCLS; c += 64) probs_s[wave][c] = expf(lrow[c] - mx) / s;
    __syncthreads();

    float4 pb = reinterpret_cast<const float4*>(pboxes)[row];
    float ax1 = pb.x - 0.5f * pb.z, ay1 = pb.y - 0.5f * pb.w;
    float ax2 = pb.x + 0.5f * pb.z, ay2 = pb.y + 0.5f * pb.w;
    float areaA = (ax2 - ax1) * (ay2 - ay1);

    float* crow = C + (size_t)row * BM;
    for (int j = lane; j < BM; j += 64) {
      int cls = tl_s[j];
      float cc = -probs_s[wave][cls];
      float4 t = tb_s[j];
      float cb = fabsf(pb.x - t.x) + fabsf(pb.y - t.y) +
                 fabsf(pb.z - t.z) + fabsf(pb.w - t.w);
      float bx1 = t.x - 0.5f * t.z, by1 = t.y - 0.5f * t.w;
      float bx2 = t.x + 0.5f * t.z, by2 = t.y + 0.5f * t.w;
      float areaB = (bx2 - bx1) * (by2 - by1);
      float iw = fmaxf(fminf(ax2, bx2) - fmaxf(ax1, bx1), 0.f);
      float ih = fmaxf(fminf(ay2, by2) - fmaxf(ay1, by1), 0.f);
      float inter = iw * ih;
      float uni = areaA + areaB - inter;
      float iou = inter / uni;
      float ew = fmaxf(fmaxf(ax2, bx2) - fminf(ax1, bx1), 0.f);
      float eh = fmaxf(fmaxf(ay2, by2) - fminf(ay1, by1), 0.f);
      float areaE = ew * eh;
      float giou = iou - (areaE - uni) / areaE;
      crow[j] = (cc + 5.f * cb) - 2.f * giou;
    }
    __syncthreads();
  }
}

// ---------------- Kernel 2: Hungarian (JV) per batch ----------------
// One block (1 wave, 64 lanes) per batch. cost (HN=50 rows x HM=300 cols)
// = C[b, j, b*50+i] transposed into LDS. Lane owns cols j = lane + 64k.
__global__ __launch_bounds__(64) void hungarian_kernel(
    const float* __restrict__ C, float* __restrict__ outp) {
  __shared__ float hc[HN * PITCH];  // 60800 B
  __shared__ float u[HN + 1];
  __shared__ int   p[HM + 1];
  __shared__ int   way[HM];
  __shared__ int   qarr[HN];

  int b = blockIdx.x;
  int lane = threadIdx.x;
  const float* Cb = C + (size_t)b * NQ * BM + (size_t)b * NM;

  // load 50x300 submatrix (transposed) via float2
  for (int idx = lane; idx < HM * (HN / 2); idx += 64) {
    int j = idx / (HN / 2);
    int h = idx - j * (HN / 2);
    float2 v2 = *reinterpret_cast<const float2*>(Cb + (size_t)j * BM + 2 * h);
    hc[(2 * h) * PITCH + j]     = v2.x;
    hc[(2 * h + 1) * PITCH + j] = v2.y;
  }
  for (int i = lane; i <= HN; i += 64) u[i] = 0.f;
  for (int j = lane; j <= HM; j += 64) p[j] = -1;
  __syncthreads();

  float v_r[5], minv_r[5];
#pragma unroll
  for (int k = 0; k < 5; k++) v_r[k] = 0.f;

  for (int i = 0; i < HN; i++) {
    unsigned usedbits = 0;
#pragma unroll
    for (int k = 0; k < 5; k++) minv_r[k] = BIG;
    if (lane == 0) p[HM] = i;
    __syncthreads();

    int j0 = HM;
    while (true) {
      int i0 = p[j0];         // uniform broadcast read
      float ui0 = u[i0];
      if (lane == (j0 & 63)) usedbits |= (1u << (j0 >> 6));  // mark used

      float best = BIG;
      int bj = 0x7fffffff;
#pragma unroll
      for (int k = 0; k < 5; k++) {
        int j = lane + 64 * k;
        bool used = (usedbits >> k) & 1u;
        if (j < HM && !used) {
          float cur = (hc[i0 * PITCH + j] - ui0) - v_r[k];
          if (cur < minv_r[k]) { minv_r[k] = cur; way[j] = j0; }
          if (minv_r[k] < best) { best = minv_r[k]; bj = j; }
        }
      }
      // wave argmin, first-index tie-break (matches jnp.argmin)
#pragma unroll
      for (int m = 1; m < 64; m <<= 1) {
        float ov = __shfl_xor(best, m, 64);
        int oj = __shfl_xor(bj, m, 64);
        if (ov < best || (ov == best && oj < bj)) { best = ov; bj = oj; }
      }
      float delta = best;
      int j1 = bj;

      // dual updates (ref order: u[p[used]] += delta; v[used] -= delta;
      // minv[!used] -= delta)
#pragma unroll
      for (int k = 0; k < 5; k++) {
        int j = lane + 64 * k;
        bool used = (usedbits >> k) & 1u;
        if (j <= HM) {
          if (used) {
            v_r[k] -= delta;
            u[p[j]] += delta;   // distinct rows per used col: no collision
          } else if (j < HM) {
            minv_r[k] -= delta;
          }
        }
      }
      __syncthreads();
      j0 = j1;
      if (p[j0] == -1) break;
    }

    // augment along `way` (all lanes run identical walk; same-value writes)
    int jj = j0;
    while (jj != HM) {
      int jn = way[jj];
      p[jj] = p[jn];
      jj = jn;
    }
    __syncthreads();
  }

  // q[i] = column assigned to row i
  for (int j = lane; j < HM; j += 64) {
    int r = p[j];
    if (r >= 0) qarr[r] = j;
  }
  __syncthreads();

  // argsort(q) via exact ranks (q entries distinct); emit as float32
  if (lane < HN) {
    int qi = qarr[lane];
    int rank = 0;
    for (int t = 0; t < HN; t++) rank += (qarr[t] < qi);
    outp[(size_t)b * NM + rank] = (float)qi;        // pred_idx
    outp[BM + (size_t)b * NM + rank] = (float)lane; // gt_idx
  }
}

extern "C" void kernel_launch(void* const* d_in, const int* in_sizes, int n_in,
                              void* d_out, int out_size, void* d_ws, size_t ws_size,
                              hipStream_t stream) {
  const float* logits = (const float*)d_in[0];   // (32,300,92)
  const float* pboxes = (const float*)d_in[1];   // (32,300,4)
  const int*   tlab   = (const int*)d_in[2];     // (32,50)
  const float* tbox   = (const float*)d_in[3];   // (32,50,4)
  float* out = (float*)d_out;
  float* C = out + 2 * BM;                       // C after pred_idx, gt_idx

  cost_kernel<<<dim3(BQ / ROWS_PER_BLOCK), dim3(256), 0, stream>>>(
      logits, pboxes, tlab, tbox, C);
  hungarian_kernel<<<dim3(NB), dim3(64), 0, stream>>>(C, out);
}

// Round 2
// 174.084 us; speedup vs baseline: 1.3738x; 1.3738x over previous
//
#include <hip/hip_runtime.h>
#include <hip/hip_bf16.h>

#define NB   32
#define NQ   300
#define NCLS 92
#define NM   50
#define BM   (NB * NM)   // 1600 flat targets
#define BQ   (NB * NQ)   // 9600 flat preds
#define HM   NQ          // hungarian cols (queries) = 300
#define HN   NM          // hungarian rows (targets) = 50
#define PITCH 305        // 305 % 32 = 17 (odd): row-scan conflict-free, col-mode 2-way (free)
#define BIG  1e30f

__device__ __forceinline__ float wred_max(float v) {
#pragma unroll
  for (int m = 1; m < 64; m <<= 1) v = fmaxf(v, __shfl_xor(v, m, 64));
  return v;
}
__device__ __forceinline__ float wred_sum(float v) {
#pragma unroll
  for (int m = 1; m < 64; m <<= 1) v += __shfl_xor(v, m, 64);
  return v;
}
__device__ __forceinline__ float wred_min(float v) {
#pragma unroll
  for (int m = 1; m < 64; m <<= 1) v = fminf(v, __shfl_xor(v, m, 64));
  return v;
}

// ---------------- Kernel 1: cost matrix ----------------
// One wave per pred row, no block-wide barriers. float4 stores.
__global__ __launch_bounds__(256) void cost_kernel(
    const float* __restrict__ logits, const float* __restrict__ pboxes,
    const int* __restrict__ tlab, const float* __restrict__ tbox,
    float* __restrict__ C) {
  __shared__ float probs_s[4][NCLS];
  int lane = threadIdx.x & 63, wave = threadIdx.x >> 6;
  int row = blockIdx.x * 4 + wave;

  const float* lrow = logits + (size_t)row * NCLS;
  float x0 = (lane < NCLS) ? lrow[lane] : -BIG;
  float x1 = (lane + 64 < NCLS) ? lrow[lane + 64] : -BIG;
  float mx = wred_max(fmaxf(x0, x1));
  float e0 = expf(x0 - mx), e1 = expf(x1 - mx);
  float s = wred_sum(e0 + e1);
  if (lane < NCLS) probs_s[wave][lane] = e0 / s;
  if (lane + 64 < NCLS) probs_s[wave][lane + 64] = e1 / s;
  __threadfence_block();  // wave-coherent LDS; no cross-wave sharing

  float4 pb = reinterpret_cast<const float4*>(pboxes)[row];
  float ax1 = pb.x - 0.5f * pb.z, ay1 = pb.y - 0.5f * pb.w;
  float ax2 = pb.x + 0.5f * pb.z, ay2 = pb.y + 0.5f * pb.w;
  float areaA = (ax2 - ax1) * (ay2 - ay1);

  const float4* tbv = reinterpret_cast<const float4*>(tbox);
  const int4*   tlv = reinterpret_cast<const int4*>(tlab);
  float4* crow = reinterpret_cast<float4*>(C + (size_t)row * BM);
  for (int q4 = lane; q4 < BM / 4; q4 += 64) {
    int4 cls = tlv[q4];
    int clsa[4] = {cls.x, cls.y, cls.z, cls.w};
    float4 o;
    float* op = &o.x;
#pragma unroll
    for (int e = 0; e < 4; e++) {
      float4 t = tbv[q4 * 4 + e];
      float cc = -probs_s[wave][clsa[e]];
      float cb = fabsf(pb.x - t.x) + fabsf(pb.y - t.y) +
                 fabsf(pb.z - t.z) + fabsf(pb.w - t.w);
      float bx1 = t.x - 0.5f * t.z, by1 = t.y - 0.5f * t.w;
      float bx2 = t.x + 0.5f * t.z, by2 = t.y + 0.5f * t.w;
      float areaB = (bx2 - bx1) * (by2 - by1);
      float iw = fmaxf(fminf(ax2, bx2) - fmaxf(ax1, bx1), 0.f);
      float ih = fmaxf(fminf(ay2, by2) - fmaxf(ay1, by1), 0.f);
      float inter = iw * ih;
      float uni = areaA + areaB - inter;
      float iou = inter / uni;
      float ew = fmaxf(fmaxf(ax2, bx2) - fminf(ax1, bx1), 0.f);
      float eh = fmaxf(fmaxf(ay2, by2) - fminf(ay1, by1), 0.f);
      float areaE = ew * eh;
      float giou = iou - (areaE - uni) / areaE;
      op[e] = (cc + 5.f * cb) - 2.f * giou;
    }
    crow[q4] = o;
  }
}

// ---------------- Kernel 2: Hungarian (LAPJV-style) per batch ----------------
// Row reduction + greedy tight-edge pre-assignment, then JV augmenting search
// only for the ~5 colliding rows. One wave per batch.
__global__ __launch_bounds__(64) void hungarian_kernel(
    const float* __restrict__ C, float* __restrict__ outp) {
  __shared__ float hc[HN * PITCH];  // 61000 B
  __shared__ float u[HN + 1];
  __shared__ int   p[HM + 1];
  __shared__ int   way[HM];
  __shared__ int   am[HN];
  __shared__ int   pend[HN];
  __shared__ int   qarr[HN];

  int b = blockIdx.x, lane = threadIdx.x;
  const float* Cb = C + (size_t)b * NQ * BM + (size_t)b * NM;

  // load 50x300 submatrix (transposed) via float2
  for (int idx = lane; idx < HM * (HN / 2); idx += 64) {
    int j = idx / (HN / 2);
    int h = idx - j * (HN / 2);
    float2 v2 = *reinterpret_cast<const float2*>(Cb + (size_t)j * BM + 2 * h);
    hc[(2 * h) * PITCH + j]     = v2.x;
    hc[(2 * h + 1) * PITCH + j] = v2.y;
  }
  for (int j = lane; j <= HM; j += 64) p[j] = -1;
  if (lane == 0) u[HN] = 0.f;
  __syncthreads();

  // row reduction: lane i scans its row (banks conflict-free via PITCH)
  if (lane < HN) {
    float mn = BIG; int amv = 0;
    for (int j = 0; j < HM; j++) {
      float vv = hc[lane * PITCH + j];
      if (vv < mn) { mn = vv; amv = j; }
    }
    u[lane] = mn; am[lane] = amv;
  }
  __syncthreads();

  // greedy tight-edge assignment (uniform across lanes, same-value writes)
  int npend = 0;
  for (int i = 0; i < HN; i++) {
    int jm = am[i];
    if (p[jm] == -1) p[jm] = i;
    else pend[npend++] = i;
  }
  __syncthreads();

  float v_r[5], minv_r[5];
#pragma unroll
  for (int k = 0; k < 5; k++) v_r[k] = 0.f;

  for (int t = 0; t < npend; t++) {
    int i_start = pend[t];
    unsigned usedbits = 0;
#pragma unroll
    for (int k = 0; k < 5; k++) minv_r[k] = BIG;
    if (lane == 0) p[HM] = i_start;
    __syncthreads();

    int j0 = HM;
    while (true) {
      int i0 = p[j0];
      float ui0 = u[i0];
      if (lane == (j0 & 63)) usedbits |= 1u << (j0 >> 6);

      float best = BIG; int bj = 0;
#pragma unroll
      for (int k = 0; k < 5; k++) {
        int j = lane + 64 * k;
        if (j < HM && !((usedbits >> k) & 1u)) {
          float cur = hc[i0 * PITCH + j] - ui0 - v_r[k];
          if (cur < minv_r[k]) { minv_r[k] = cur; way[j] = j0; }
          if (minv_r[k] < best) { best = minv_r[k]; bj = j; }
        }
      }
      // value-only wave min, then first-lane index resolve (ties measure-zero;
      // any tie choice yields an optimal path -> same unique optimum)
      float wmin = wred_min(best);
      unsigned long long ball = __ballot(best == wmin);
      int src = (int)__ffsll(ball) - 1;
      int j1 = __shfl(bj, src, 64);
      float delta = wmin;

#pragma unroll
      for (int k = 0; k < 5; k++) {
        int j = lane + 64 * k;
        if (j <= HM) {
          if ((usedbits >> k) & 1u) {
            v_r[k] -= delta;
            u[p[j]] += delta;   // distinct rows per used col: no collision
          } else if (j < HM) {
            minv_r[k] -= delta;
          }
        }
      }
      __syncthreads();
      j0 = j1;
      if (p[j0] == -1) break;
    }

    // augment along `way` (all lanes identical walk; same-value writes)
    int jj = j0;
    while (jj != HM) {
      int jn = way[jj];
      p[jj] = p[jn];
      jj = jn;
    }
    __syncthreads();
  }

  // q[i] = column assigned to row i
  for (int j = lane; j < HM; j += 64) {
    int r = p[j];
    if (r >= 0) qarr[r] = j;
  }
  __syncthreads();

  // argsort(q) via exact ranks; emit as float32
  if (lane < HN) {
    int qi = qarr[lane];
    int rank = 0;
    for (int tt = 0; tt < HN; tt++) rank += (qarr[tt] < qi);
    outp[(size_t)b * NM + rank] = (float)qi;        // pred_idx
    outp[BM + (size_t)b * NM + rank] = (float)lane; // gt_idx
  }
}

extern "C" void kernel_launch(void* const* d_in, const int* in_sizes, int n_in,
                              void* d_out, int out_size, void* d_ws, size_t ws_size,
                              hipStream_t stream) {
  const float* logits = (const float*)d_in[0];   // (32,300,92)
  const float* pboxes = (const float*)d_in[1];   // (32,300,4)
  const int*   tlab   = (const int*)d_in[2];     // (32,50)
  const float* tbox   = (const float*)d_in[3];   // (32,50,4)
  float* out = (float*)d_out;
  float* C = out + 2 * BM;                       // C after pred_idx, gt_idx

  cost_kernel<<<dim3(BQ / 4), dim3(256), 0, stream>>>(
      logits, pboxes, tlab, tbox, C);
  hungarian_kernel<<<dim3(NB), dim3(64), 0, stream>>>(C, out);
}

// Round 6
// 128.946 us; speedup vs baseline: 1.8547x; 1.3501x over previous
//
#include <hip/hip_runtime.h>
#include <hip/hip_bf16.h>

#define NB   32
#define NQ   300
#define NCLS 92
#define NM   50
#define BM   (NB * NM)   // 1600 flat targets
#define BQ   (NB * NQ)   // 9600 flat preds
#define HM   NQ          // hungarian cols (queries) = 300
#define HN   NM          // hungarian rows (targets) = 50
#define PITCH 305        // 305 % 32 = 17 (odd): row-scan & col-mode <=2-way (free)
#define BIG  1e30f
#define HUNG_BLOCKS NB
#define COST_ROWS_PER_BLOCK 16
#define COST_BLOCKS (BQ / COST_ROWS_PER_BLOCK)  // 600
#define NBLOCKS (HUNG_BLOCKS + COST_BLOCKS)     // 632

typedef float vf4 __attribute__((ext_vector_type(4)));

// single-wave fence: equivalent to __syncthreads() when one wave executes
#define FENCE() __threadfence_block()

__device__ __forceinline__ float wred_max(float v) {
#pragma unroll
  for (int m = 1; m < 64; m <<= 1) v = fmaxf(v, __shfl_xor(v, m, 64));
  return v;
}
__device__ __forceinline__ float wred_sum(float v) {
#pragma unroll
  for (int m = 1; m < 64; m <<= 1) v += __shfl_xor(v, m, 64);
  return v;
}
__device__ __forceinline__ float wred_min(float v) {
#pragma unroll
  for (int m = 1; m < 64; m <<= 1) v = fminf(v, __shfl_xor(v, m, 64));
  return v;
}

// cost(pred, target): -prob + 5*L1 - 2*GIoU  — R2-identical precise arithmetic
__device__ __forceinline__ float pair_cost(float ax1, float ay1, float ax2,
                                           float ay2, float areaA,
                                           const float4& pb, const float4& t,
                                           float negprob) {
  float cb = fabsf(pb.x - t.x) + fabsf(pb.y - t.y) +
             fabsf(pb.z - t.z) + fabsf(pb.w - t.w);
  float bx1 = t.x - 0.5f * t.z, by1 = t.y - 0.5f * t.w;
  float bx2 = t.x + 0.5f * t.z, by2 = t.y + 0.5f * t.w;
  float areaB = (bx2 - bx1) * (by2 - by1);
  float iw = fmaxf(fminf(ax2, bx2) - fmaxf(ax1, bx1), 0.f);
  float ih = fmaxf(fminf(ay2, by2) - fmaxf(ay1, by1), 0.f);
  float inter = iw * ih;
  float uni = areaA + areaB - inter;
  float iou = inter / uni;
  float ew = fmaxf(fmaxf(ax2, bx2) - fminf(ax1, bx1), 0.f);
  float eh = fmaxf(fmaxf(ay2, by2) - fminf(ay1, by1), 0.f);
  float areaE = ew * eh;
  float giou = iou - (areaE - uni) / areaE;
  return (negprob + 5.f * cb) - 2.f * giou;
}

// wave-cooperative softmax over 92 classes -> prow[0..91] (precise expf, div)
__device__ __forceinline__ void wave_softmax(const float* __restrict__ lrow,
                                             float* prow, int lane) {
  float x0 = (lane < NCLS) ? lrow[lane] : -BIG;
  float x1 = (lane + 64 < NCLS) ? lrow[lane + 64] : -BIG;
  float mx = wred_max(fmaxf(x0, x1));
  float e0 = expf(x0 - mx), e1 = expf(x1 - mx);
  float s = wred_sum(e0 + e1);
  if (lane < NCLS) prow[lane] = e0 / s;
  if (lane + 64 < NCLS) prow[lane + 64] = e1 / s;
  FENCE();
}

__global__ __launch_bounds__(1024) void fused_kernel(
    const float* __restrict__ logits, const float* __restrict__ pboxes,
    const int* __restrict__ tlab, const float* __restrict__ tbox,
    float* __restrict__ outp) {
  __shared__ float hc[HN * PITCH];      // 61000 B (hungarian path only)
  __shared__ float probs_s[16][NCLS];   // 5888 B (both paths)
  __shared__ float u[HN + 1];
  __shared__ int   p[HM + 1];
  __shared__ int   way[HM];
  __shared__ int   am[HN];
  __shared__ int   pend[HN];
  __shared__ int   qarr[HN];

  float* C = outp + 2 * BM;
  int tid = threadIdx.x, wave = tid >> 6, lane = tid & 63;

  if (blockIdx.x >= HUNG_BLOCKS) {
    // ---------------- cost-matrix path: one pred row per wave ----------------
    int row = (blockIdx.x - HUNG_BLOCKS) * COST_ROWS_PER_BLOCK + wave;
    wave_softmax(logits + (size_t)row * NCLS, probs_s[wave], lane);

    float4 pb = reinterpret_cast<const float4*>(pboxes)[row];
    float ax1 = pb.x - 0.5f * pb.z, ay1 = pb.y - 0.5f * pb.w;
    float ax2 = pb.x + 0.5f * pb.z, ay2 = pb.y + 0.5f * pb.w;
    float areaA = (ax2 - ax1) * (ay2 - ay1);

    const float4* tbv = reinterpret_cast<const float4*>(tbox);
    const int4*   tlv = reinterpret_cast<const int4*>(tlab);
    vf4* crow = reinterpret_cast<vf4*>(C + (size_t)row * BM);
    for (int q4 = lane; q4 < BM / 4; q4 += 64) {
      int4 cls = tlv[q4];
      int clsa[4] = {cls.x, cls.y, cls.z, cls.w};
      vf4 o;
#pragma unroll
      for (int e = 0; e < 4; e++) {
        float4 t = tbv[q4 * 4 + e];
        o[e] = pair_cost(ax1, ay1, ax2, ay2, areaA, pb, t,
                         -probs_s[wave][clsa[e]]);
      }
      __builtin_nontemporal_store(o, &crow[q4]);
    }
    return;
  }

  // ---------------- hungarian path: batch b = blockIdx.x ----------------
  int b = blockIdx.x;

  // init p (all threads; covered by the barrier below)
  for (int x = tid; x <= HM; x += 1024) p[x] = -1;
  if (tid == 0) u[HN] = 0.f;

  // preload this batch's 50 targets into lane registers
  float4 t_reg = make_float4(0.f, 0.f, 0.f, 0.f);
  int cls_reg = 0;
  if (lane < NM) {
    t_reg = reinterpret_cast<const float4*>(tbox)[b * NM + lane];
    cls_reg = tlab[b * NM + lane];
  }

  // stage hc[i][q] = cost(pred (b,q), target (b,i)) with all 16 waves
  const float4* pbv = reinterpret_cast<const float4*>(pboxes);
  for (int q = wave; q < NQ; q += 16) {
    wave_softmax(logits + (size_t)(b * NQ + q) * NCLS, probs_s[wave], lane);
    float4 pb = pbv[b * NQ + q];
    float ax1 = pb.x - 0.5f * pb.z, ay1 = pb.y - 0.5f * pb.w;
    float ax2 = pb.x + 0.5f * pb.z, ay2 = pb.y + 0.5f * pb.w;
    float areaA = (ax2 - ax1) * (ay2 - ay1);
    if (lane < NM) {
      float negp = -probs_s[wave][cls_reg];
      hc[lane * PITCH + q] =
          pair_cost(ax1, ay1, ax2, ay2, areaA, pb, t_reg, negp);
    }
  }
  __syncthreads();            // all 16 waves alive here
  if (wave != 0) return;      // wave 0 continues barrier-free (single wave)

  // ======== R2-verbatim LAPJV (LDS u/p/way, v=0 start, row-argmin greedy) ====

  // row reduction: lane i scans its row
  if (lane < HN) {
    float mn = BIG; int amv = 0;
    for (int j = 0; j < HM; j++) {
      float vv = hc[lane * PITCH + j];
      if (vv < mn) { mn = vv; amv = j; }
    }
    u[lane] = mn; am[lane] = amv;
  }
  FENCE();

  // greedy tight-edge assignment (uniform across lanes, same-value writes)
  int npend = 0;
  for (int i = 0; i < HN; i++) {
    int jm = am[i];
    if (p[jm] == -1) p[jm] = i;
    else pend[npend++] = i;
  }
  FENCE();

  float v_r[5], minv_r[5];
#pragma unroll
  for (int k = 0; k < 5; k++) v_r[k] = 0.f;

  for (int t = 0; t < npend; t++) {
    int i_start = pend[t];
    unsigned usedbits = 0;
#pragma unroll
    for (int k = 0; k < 5; k++) minv_r[k] = BIG;
    if (lane == 0) p[HM] = i_start;
    FENCE();

    int j0 = HM;
    while (true) {
      int i0 = p[j0];
      float ui0 = u[i0];
      if (lane == (j0 & 63)) usedbits |= 1u << (j0 >> 6);

      float best = BIG; int bj = 0;
#pragma unroll
      for (int k = 0; k < 5; k++) {
        int j = lane + 64 * k;
        if (j < HM && !((usedbits >> k) & 1u)) {
          float cur = hc[i0 * PITCH + j] - ui0 - v_r[k];
          if (cur < minv_r[k]) { minv_r[k] = cur; way[j] = j0; }
          if (minv_r[k] < best) { best = minv_r[k]; bj = j; }
        }
      }
      float wmin = wred_min(best);
      unsigned long long ball = __ballot(best == wmin);
      int src = (int)__ffsll((long long)ball) - 1;
      int j1 = __shfl(bj, src, 64);
      float delta = wmin;

      // dual updates (used set EXCLUDES j1, matching ref ordering);
      // j == HM (virtual col) contributes u[i_start] += delta
#pragma unroll
      for (int k = 0; k < 5; k++) {
        int j = lane + 64 * k;
        if (j <= HM) {
          if ((usedbits >> k) & 1u) {
            v_r[k] -= delta;
            u[p[j]] += delta;   // distinct rows per used col: no collision
          } else if (j < HM) {
            minv_r[k] -= delta;
          }
        }
      }
      FENCE();
      j0 = j1;
      if (p[j0] == -1) break;
    }

    // augment along `way` (all lanes identical walk; same-value writes)
    int jj = j0;
    while (jj != HM) {
      int jn = way[jj];
      p[jj] = p[jn];
      jj = jn;
    }
    FENCE();
  }

  // ---- emit: q[i] = col of row i; rank-sort; write as float32 ----
  for (int j = lane; j < HM; j += 64) {
    int r = p[j];
    if (r >= 0) qarr[r] = j;
  }
  FENCE();
  if (lane < HN) {
    int qi = qarr[lane];
    int rank = 0;
    for (int t = 0; t < HN; t++) rank += (qarr[t] < qi);
    outp[(size_t)b * NM + rank] = (float)qi;         // pred_idx
    outp[BM + (size_t)b * NM + rank] = (float)lane;  // gt_idx
  }
}

extern "C" void kernel_launch(void* const* d_in, const int* in_sizes, int n_in,
                              void* d_out, int out_size, void* d_ws, size_t ws_size,
                              hipStream_t stream) {
  const float* logits = (const float*)d_in[0];   // (32,300,92)
  const float* pboxes = (const float*)d_in[1];   // (32,300,4)
  const int*   tlab   = (const int*)d_in[2];     // (32,50)
  const float* tbox   = (const float*)d_in[3];   // (32,50,4)
  float* out = (float*)d_out;

  fused_kernel<<<dim3(NBLOCKS), dim3(1024), 0, stream>>>(
      logits, pboxes, tlab, tbox, out);
}